// Round 13
// baseline (105.674 us; speedup 1.0000x reference)
//
#include <hip/hip_runtime.h>
#include <math.h>

typedef unsigned char u8;
typedef unsigned int u32;
typedef __attribute__((ext_vector_type(8))) int i32x8;
typedef __attribute__((ext_vector_type(4))) float f32x4;

#define SC1 0x7F7F7F7F   // e8m0 scale bytes = 127 -> 2^0 = 1.0
#define CPB 1024         // cols per block
#define NCT 8            // col-tiles (128 cols each) per block

// ---------- helpers ----------

__device__ __forceinline__ u32 ordf(float f) {
    u32 u = __float_as_uint(f);
    return (u & 0x80000000u) ? ~u : (u | 0x80000000u);
}
__device__ __forceinline__ float unordf(u32 u) {
    u = (u & 0x80000000u) ? (u & 0x7FFFFFFFu) : ~u;
    return __uint_as_float(u);
}

// f32 -> OCP e4m3fn with RNE. Assumes finite |x| <= 1.
__device__ __forceinline__ u32 f2e4m3(float x) {
    u32 u = __float_as_uint(x);
    u32 sgn = (u >> 24) & 0x80u;
    int ne = (int)((u >> 23) & 0xFF) - 120;   // e4m3 biased exponent
    if (ne >= 1) {
        u32 m = u & 0x7FFFFFu;
        u32 keep = m >> 20;
        u32 rest = m & 0xFFFFFu;
        keep += (rest > 0x80000u) || (rest == 0x80000u && (keep & 1u));
        if (keep == 8u) { keep = 0u; ne += 1; }
        return sgn | ((u32)ne << 3) | keep;
    }
    float ax = __uint_as_float(u & 0x7FFFFFFFu);
    u32 f = (u32)__builtin_rintf(ax * 512.0f);
    if (f >= 8u) return sgn | 0x08u;
    return sgn | f;
}

// ---------- kernel 1: normalize rows -> fp8 e4m3; init rowmax ----------

__global__ __launch_bounds__(256) void norm_kernel(
    const float* __restrict__ feat, const float* __restrict__ memf,
    u8* __restrict__ fb, u8* __restrict__ mb, u32* __restrict__ rowmax,
    int N, int M, int D)
{
    const int lane = threadIdx.x & 63;
    const int wid  = threadIdx.x >> 6;
    const int rid  = blockIdx.x * 4 + wid;
    if (rid >= N + M) return;

    const float* src;
    u8* dst;
    if (rid < N) { src = feat + (size_t)rid * D; dst = fb + (size_t)rid * D; }
    else         { src = memf + (size_t)(rid - N) * D; dst = mb + (size_t)(rid - N) * D; }

    float4 v0 = *(const float4*)(src + lane * 8);
    float4 v1 = *(const float4*)(src + lane * 8 + 4);
    float ss = v0.x*v0.x + v0.y*v0.y + v0.z*v0.z + v0.w*v0.w
             + v1.x*v1.x + v1.y*v1.y + v1.z*v1.z + v1.w*v1.w;
    #pragma unroll
    for (int m = 1; m <= 32; m <<= 1) ss += __shfl_xor(ss, m);

    float inv = 1.0f / fmaxf(sqrtf(ss), 1e-8f);

    u32 w0 =  f2e4m3(v0.x * inv)        | (f2e4m3(v0.y * inv) << 8)
           | (f2e4m3(v0.z * inv) << 16) | (f2e4m3(v0.w * inv) << 24);
    u32 w1 =  f2e4m3(v1.x * inv)        | (f2e4m3(v1.y * inv) << 8)
           | (f2e4m3(v1.z * inv) << 16) | (f2e4m3(v1.w * inv) << 24);
    *(uint2*)(dst + lane * 8) = make_uint2(w0, w1);

    if (rid < N && lane == 0) rowmax[rid] = 0u;   // below any real sim
}

// ---------- kernel 2: BARRIER-FREE A-in-regs, B-direct-from-L2 GEMM ----------
// Block = 128 rows x 1024 cols; 4 waves (2 row x 2 col halves); grid (8,64)
// = 512 blocks = 2/CU. blockIdx.x == XCD (bid%8 dispatch) -> each XCD reads
// ONE 1024-col B slice = 1MB fp8, L2-resident.
// A: 64 rows x K=512 per wave in regs (areg[4][4] i32x8 = 128 VGPR).
// B: fragments loaded DIRECTLY from global (L2) per MFMA - no LDS, no
// barriers, no vmcnt in the whole main loop; waves free-run.
// B-frag for 16x16x128: lane l reads B[col0+(l&15)][(l>>4)*32 .. +31].
// 2-deep P/Q register pipeline: MFMA cluster s, then issue loads for s+2
// (consumed 2 clusters later -> ~280cyc MFMA covers ~225cyc L2 latency).
// MFMA: mfma_scale_f32_16x16x128_f8f6f4, e4m3, scale 1.0 (r7-verified).

#define LDB(v0, v1, ct, kt, h) do { \
    const u8* p_ = gBw + (size_t)(((ct) * 128 + (h) * 32)) * D + (kt) * 128; \
    v0 = *(const i32x8*)(p_); \
    v1 = *(const i32x8*)(p_ + (size_t)16 * D); \
  } while (0)

#define MM(v0, v1, kt, h) do { \
    _Pragma("unroll") \
    for (int i_ = 0; i_ < 4; ++i_) { \
      acc[i_][(h)*2]   = __builtin_amdgcn_mfma_scale_f32_16x16x128_f8f6f4( \
          areg[i_][kt], v0, acc[i_][(h)*2],   0, 0, 0, SC1, 0, SC1); \
      acc[i_][(h)*2+1] = __builtin_amdgcn_mfma_scale_f32_16x16x128_f8f6f4( \
          areg[i_][kt], v1, acc[i_][(h)*2+1], 0, 0, 0, SC1, 0, SC1); \
    } } while (0)

__global__ __launch_bounds__(256, 2) void gemm_max_kernel(
    const u8* __restrict__ fb, const u8* __restrict__ mb,
    u32* __restrict__ rowmax, int N, int M, int D)
{
    __shared__ float red[256];   // [128][2] epilogue reduce only

    const int tid  = threadIdx.x;
    const int lane = tid & 63;
    const int wid  = tid >> 6;
    const int wwr  = wid >> 1;      // row-half (0..1): rows wwr*64..+63
    const int wwc  = wid & 1;       // col-half (0..1): cols wwc*64..+63 per ct
    const int l15  = lane & 15;
    const int l4   = lane >> 4;
    const int n0   = blockIdx.y * 128;
    const int m0   = blockIdx.x * CPB;

    // ---- A stripe into regs (64 rows x K=512 per wave) ----
    const u8* gA = fb + (size_t)(n0 + wwr * 64 + l15) * D + l4 * 32;
    i32x8 areg[4][4];   // [row-frag i][k-tile kt] = 128 VGPR
    #pragma unroll
    for (int i = 0; i < 4; ++i)
        #pragma unroll
        for (int kt = 0; kt < 4; ++kt)
            areg[i][kt] = *(const i32x8*)(gA + (size_t)(i * 16) * D + kt * 128);

    // ---- per-lane B fragment base ----
    const u8* gBw = mb + (size_t)(m0 + wwc * 64 + l15) * D + l4 * 32;

    f32x4 acc[4][4] = {};
    float vmax[4][4];
    #pragma unroll
    for (int i = 0; i < 4; ++i)
        #pragma unroll
        for (int rr = 0; rr < 4; ++rr) vmax[i][rr] = -1e30f;

    i32x8 P0, P1, Q0, Q1;
    LDB(P0, P1, 0, 0, 0);
    LDB(Q0, Q1, 0, 0, 1);

    #pragma unroll 1
    for (int ct = 0; ct < NCT; ++ct) {
        const int cn = (ct + 1 < NCT) ? ct + 1 : ct;   // clamped prefetch

        MM(P0, P1, 0, 0);  LDB(P0, P1, ct, 1, 0);
        MM(Q0, Q1, 0, 1);  LDB(Q0, Q1, ct, 1, 1);
        MM(P0, P1, 1, 0);  LDB(P0, P1, ct, 2, 0);
        MM(Q0, Q1, 1, 1);  LDB(Q0, Q1, ct, 2, 1);
        MM(P0, P1, 2, 0);  LDB(P0, P1, ct, 3, 0);
        MM(Q0, Q1, 2, 1);  LDB(Q0, Q1, ct, 3, 1);
        MM(P0, P1, 3, 0);  LDB(P0, P1, cn, 0, 0);
        MM(Q0, Q1, 3, 1);  LDB(Q0, Q1, cn, 0, 1);

        // fold this 128-col tile into running max; reset acc
        #pragma unroll
        for (int i = 0; i < 4; ++i)
            #pragma unroll
            for (int rr = 0; rr < 4; ++rr) {
                float v = fmaxf(fmaxf(acc[i][0][rr], acc[i][1][rr]),
                                fmaxf(acc[i][2][rr], acc[i][3][rr]));
                vmax[i][rr] = fmaxf(vmax[i][rr], v);
            }
        #pragma unroll
        for (int i = 0; i < 4; ++i)
            #pragma unroll
            for (int j = 0; j < 4; ++j) acc[i][j] = (f32x4)0.0f;
    }

    // ---- epilogue: cross-lane + cross-wave max reduce; one atomic/row ----
    #pragma unroll
    for (int i = 0; i < 4; ++i) {
        #pragma unroll
        for (int rr = 0; rr < 4; ++rr) {
            float v = vmax[i][rr];
            v = fmaxf(v, __shfl_xor(v, 1));
            v = fmaxf(v, __shfl_xor(v, 2));
            v = fmaxf(v, __shfl_xor(v, 4));
            v = fmaxf(v, __shfl_xor(v, 8));
            if (l15 == 0) {
                int rloc = wwr * 64 + i * 16 + l4 * 4 + rr;
                red[rloc * 2 + wwc] = v;
            }
        }
    }
    __syncthreads();
    if (tid < 128) {
        float v = fmaxf(red[tid * 2 + 0], red[tid * 2 + 1]);
        atomicMax(&rowmax[n0 + tid], ordf(v));
    }
}

// ---------- kernel 3a: BCE + novelty weight, per-block partial sums ----------

__global__ __launch_bounds__(256) void finalize1_kernel(
    const float* __restrict__ pred, const float* __restrict__ targ,
    const u32* __restrict__ rowmax, float* __restrict__ partial, int N)
{
    __shared__ float ws4[4];
    const int tid = threadIdx.x;
    const int i = blockIdx.x * 256 + tid;

    float sv = 0.f;
    if (i < N) {
        float x = pred[i];
        float t = targ[i];
        float bl = fmaxf(x, 0.f) + log1pf(expf(-fabsf(x))) - x * t;
        float ms = unordf(rowmax[i]);
        sv = bl * (1.0f + 2.0f * (1.0f - ms));
    }
    #pragma unroll
    for (int m = 1; m <= 32; m <<= 1) sv += __shfl_xor(sv, m);
    if ((tid & 63) == 0) ws4[tid >> 6] = sv;
    __syncthreads();
    if (tid == 0) partial[blockIdx.x] = ws4[0] + ws4[1] + ws4[2] + ws4[3];
}

// ---------- kernel 3b: final reduce ----------

__global__ __launch_bounds__(64) void finalize2_kernel(
    const float* __restrict__ partial, float* __restrict__ out, int nb, int N)
{
    float sv = 0.f;
    for (int i = threadIdx.x; i < nb; i += 64) sv += partial[i];
    #pragma unroll
    for (int m = 1; m <= 32; m <<= 1) sv += __shfl_xor(sv, m);
    if (threadIdx.x == 0) out[0] = sv / (float)N;
}

// ---------- launch ----------

extern "C" void kernel_launch(void* const* d_in, const int* in_sizes, int n_in,
                              void* d_out, int out_size, void* d_ws, size_t ws_size,
                              hipStream_t stream) {
    const float* pred = (const float*)d_in[0];
    const float* targ = (const float*)d_in[1];
    const float* feat = (const float*)d_in[2];
    const float* memf = (const float*)d_in[3];
    const int N = in_sizes[0];
    const int D = in_sizes[2] / N;
    const int M = in_sizes[3] / D;
    float* out = (float*)d_out;

    u8* fb8 = (u8*)d_ws;                           // N*D fp8
    u8* mb8 = fb8 + (size_t)N * D;                 // M*D fp8
    u32* rowmax = (u32*)(mb8 + (size_t)M * D);     // N u32
    float* partial = (float*)(rowmax + N);         // nb floats

    const int rows = N + M;
    const int nb = (N + 255) / 256;
    norm_kernel<<<dim3((rows + 3) / 4), dim3(256), 0, stream>>>(
        feat, memf, fb8, mb8, rowmax, N, M, D);
    gemm_max_kernel<<<dim3(M / CPB, N / 128), dim3(256), 0, stream>>>(
        fb8, mb8, rowmax, N, M, D);
    finalize1_kernel<<<dim3(nb), dim3(256), 0, stream>>>(
        pred, targ, rowmax, partial, N);
    finalize2_kernel<<<dim3(1), dim3(64), 0, stream>>>(partial, out, nb, N);
}

// Round 14
// 52.832 us; speedup vs baseline: 2.0002x; 2.0002x over previous
//
#include <hip/hip_runtime.h>
#include <math.h>

typedef unsigned char u8;
typedef unsigned int u32;
typedef __attribute__((ext_vector_type(8))) int i32x8;
typedef __attribute__((ext_vector_type(4))) float f32x4;

#define SC1 0x7F7F7F7F   // e8m0 scale bytes = 127 -> 2^0 = 1.0
#define CPB 1024         // cols per block
#define NCT (CPB / 128)  // col-tiles per block = 8

// ---------- helpers ----------

__device__ __forceinline__ u32 ordf(float f) {
    u32 u = __float_as_uint(f);
    return (u & 0x80000000u) ? ~u : (u | 0x80000000u);
}
__device__ __forceinline__ float unordf(u32 u) {
    u = (u & 0x80000000u) ? (u & 0x7FFFFFFFu) : ~u;
    return __uint_as_float(u);
}

// f32 -> OCP e4m3fn with RNE. Assumes finite |x| <= 1.
__device__ __forceinline__ u32 f2e4m3(float x) {
    u32 u = __float_as_uint(x);
    u32 sgn = (u >> 24) & 0x80u;
    int ne = (int)((u >> 23) & 0xFF) - 120;   // e4m3 biased exponent
    if (ne >= 1) {
        u32 m = u & 0x7FFFFFu;
        u32 keep = m >> 20;
        u32 rest = m & 0xFFFFFu;
        keep += (rest > 0x80000u) || (rest == 0x80000u && (keep & 1u));
        if (keep == 8u) { keep = 0u; ne += 1; }
        return sgn | ((u32)ne << 3) | keep;
    }
    float ax = __uint_as_float(u & 0x7FFFFFFFu);
    u32 f = (u32)__builtin_rintf(ax * 512.0f);
    if (f >= 8u) return sgn | 0x08u;
    return sgn | f;
}

// async global->LDS, 16B per lane (dest = wave-uniform base + lane*16)
__device__ __forceinline__ void gload_lds16(const void* gsrc, void* ldst) {
    __builtin_amdgcn_global_load_lds(
        (const __attribute__((address_space(1))) void*)gsrc,
        (__attribute__((address_space(3))) void*)ldst,
        16, 0, 0);
}

__device__ __forceinline__ i32x8 ldfrag(const char* plo, const char* phi) {
    int4 lo = *(const int4*)plo;
    int4 hi = *(const int4*)phi;
    i32x8 r = {lo.x, lo.y, lo.z, lo.w, hi.x, hi.y, hi.z, hi.w};
    return r;
}

#define BARRIER do { __builtin_amdgcn_sched_barrier(0); \
                     __builtin_amdgcn_s_barrier(); \
                     __builtin_amdgcn_sched_barrier(0); } while (0)
#define VMCNT(n) do { asm volatile("s_waitcnt vmcnt(" #n ")" ::: "memory"); \
                      __builtin_amdgcn_sched_barrier(0); } while (0)

// ---------- kernel 1: normalize rows -> fp8 e4m3; init rowmax ----------

__global__ __launch_bounds__(256) void norm_kernel(
    const float* __restrict__ feat, const float* __restrict__ memf,
    u8* __restrict__ fb, u8* __restrict__ mb, u32* __restrict__ rowmax,
    int N, int M, int D)
{
    const int lane = threadIdx.x & 63;
    const int wid  = threadIdx.x >> 6;
    const int rid  = blockIdx.x * 4 + wid;
    if (rid >= N + M) return;

    const float* src;
    u8* dst;
    if (rid < N) { src = feat + (size_t)rid * D; dst = fb + (size_t)rid * D; }
    else         { src = memf + (size_t)(rid - N) * D; dst = mb + (size_t)(rid - N) * D; }

    float4 v0 = *(const float4*)(src + lane * 8);
    float4 v1 = *(const float4*)(src + lane * 8 + 4);
    float ss = v0.x*v0.x + v0.y*v0.y + v0.z*v0.z + v0.w*v0.w
             + v1.x*v1.x + v1.y*v1.y + v1.z*v1.z + v1.w*v1.w;
    #pragma unroll
    for (int m = 1; m <= 32; m <<= 1) ss += __shfl_xor(ss, m);

    float inv = 1.0f / fmaxf(sqrtf(ss), 1e-8f);

    u32 w0 =  f2e4m3(v0.x * inv)        | (f2e4m3(v0.y * inv) << 8)
           | (f2e4m3(v0.z * inv) << 16) | (f2e4m3(v0.w * inv) << 24);
    u32 w1 =  f2e4m3(v1.x * inv)        | (f2e4m3(v1.y * inv) << 8)
           | (f2e4m3(v1.z * inv) << 16) | (f2e4m3(v1.w * inv) << 24);
    *(uint2*)(dst + lane * 8) = make_uint2(w0, w1);

    if (rid < N && lane == 0) rowmax[rid] = 0u;   // below any real sim
}

// ---------- kernel 2: A-in-regs MX-fp8 GEMM + fused row-max (r9 champion
// structure + slab-granular counted residency) ----------
// Block = 128-row stripe x 1024 cols (8 col-tiles of 128). Grid (8,64)=512
// = 2 blocks/CU -> 2 waves/SIMD (inter-block TLP hides stalls).
// A: 64 rows x K=512 per wave in regs (areg[4][4] i32x8 = 128 VGPR).
// B: 64KB tile (4 kt-slabs of 16KB), single-buffered; staged kt-major so the
// oldest 4 loads/thread = slab kt0. Slab ledger replaces r9's vmcnt(0):
//   VMCNT(12)->BARRIER->compute kt0 -> VMCNT(8)->B->kt1 -> VMCNT(4)->B->kt2
//   -> VMCNT(0)->B->kt3. kt0 waits only first-slab latency; kt1-3 drain
//   under the preceding slab's MFMAs. WAR: top-of-ct barrier (all waves
//   consumed tile ct-1; MFMA issue implies lgkm-certified reads).
// Frag layout + XOR swizzle (byte ^= (row&7)<<4, pre-swizzled global source)
// verified r7-r13. MFMA: mfma_scale_f32_16x16x128_f8f6f4, e4m3, scale 1.0.

#define STAGE_B(gB) do { \
    _Pragma("unroll") \
    for (int kt_ = 0; kt_ < 4; ++kt_) \
      _Pragma("unroll") \
      for (int p_ = 0; p_ < 4; ++p_) \
        gload_lds16((gB) + (size_t)(p_ * 32) * D + kt_ * 128, \
                    &L[kt_ * 16384 + p_ * 4096 + tid * 16]); \
  } while (0)

#define SLAB(kt) do { \
    const char* Bt_ = Bbase + (kt) * 16384; \
    _Pragma("unroll") \
    for (int j_ = 0; j_ < 4; ++j_) { \
        i32x8 bfj_ = ldfrag(Bt_ + j_ * 2048 + oLo, Bt_ + j_ * 2048 + oHi); \
        _Pragma("unroll") \
        for (int i_ = 0; i_ < 4; ++i_) \
            acc[i_][j_] = __builtin_amdgcn_mfma_scale_f32_16x16x128_f8f6f4( \
                areg[i_][(kt)], bfj_, acc[i_][j_], 0, 0, 0, SC1, 0, SC1); \
    } } while (0)

__global__ __launch_bounds__(256, 2) void gemm_max_kernel(
    const u8* __restrict__ fb, const u8* __restrict__ mb,
    u32* __restrict__ rowmax, int N, int M, int D)
{
    __shared__ __align__(16) u8 L[65536];   // B tile only

    const int tid  = threadIdx.x;
    const int lane = tid & 63;
    const int wid  = tid >> 6;
    const int wwr  = wid >> 1;      // A row-half (0..1)
    const int wwc  = wid & 1;       // B col-half (0..1)
    const int l15  = lane & 15;
    const int l4   = lane >> 4;
    const int n0   = blockIdx.y * 128;
    const int m0   = blockIdx.x * CPB;

    // B staging: per-thread pre-swizzled global base (row = t8, chunk = tid&7)
    const int t8   = tid >> 3;
    const int swz  = ((tid & 7) ^ (t8 & 7)) * 16;

    // B ds_read: per-lane swizzled k-offsets (two b128 per frag)
    const int s    = (l15 & 7) << 4;
    const int oLo  = (l4 * 32) ^ s;
    const int oHi  = (l4 * 32 + 16) ^ s;
    const char* Lb = (const char*)L;
    const char* Bbase = Lb + (wwc * 64 + l15) * 128;   // + kt*16384 + j*2048

    // ---- prologue: issue B stage for ct=0, then load A stripe into regs ----
    const u8* gB0 = mb + (size_t)(m0 + t8) * D + swz;
    STAGE_B(gB0);

    const u8* gArow = fb + (size_t)(n0 + wwr * 64 + l15) * D + l4 * 32;
    i32x8 areg[4][4];   // [row-frag i][k-tile kt], 128 VGPR
    #pragma unroll
    for (int i = 0; i < 4; ++i)
        #pragma unroll
        for (int kt = 0; kt < 4; ++kt)
            areg[i][kt] = *(const i32x8*)(gArow + (size_t)(i * 16) * D + kt * 128);

    f32x4 acc[4][4] = {};
    float vmax[4][4];
    #pragma unroll
    for (int i = 0; i < 4; ++i)
        #pragma unroll
        for (int rr = 0; rr < 4; ++rr) vmax[i][rr] = -1e30f;

    for (int ct = 0; ct < NCT; ++ct) {
        if (ct > 0) {
            BARRIER;   // WAR: all waves consumed tile ct-1 (lgkm-certified)
            const u8* gB = mb + (size_t)(m0 + ct * 128 + t8) * D + swz;
            STAGE_B(gB);
        }

        // ---- slab-granular residency: counted wait + barrier per slab ----
        VMCNT(12); BARRIER;   // slab kt0 resident block-wide
        SLAB(0);
        VMCNT(8);  BARRIER;   // kt1 (drained under kt0's MFMAs)
        SLAB(1);
        VMCNT(4);  BARRIER;   // kt2
        SLAB(2);
        VMCNT(0);  BARRIER;   // kt3
        SLAB(3);

        // ---- fold this col-tile's sims into running max; reset acc ----
        #pragma unroll
        for (int i = 0; i < 4; ++i)
            #pragma unroll
            for (int rr = 0; rr < 4; ++rr) {
                float v = fmaxf(fmaxf(acc[i][0][rr], acc[i][1][rr]),
                                fmaxf(acc[i][2][rr], acc[i][3][rr]));
                vmax[i][rr] = fmaxf(vmax[i][rr], v);
            }
        #pragma unroll
        for (int i = 0; i < 4; ++i)
            #pragma unroll
            for (int j = 0; j < 4; ++j) acc[i][j] = (f32x4)0.0f;
    }

    // ---- epilogue: cross-lane + cross-wave max reduce; one atomic/row ----
    BARRIER;                      // protect L reuse
    float* red = (float*)L;       // [128][2]
    #pragma unroll
    for (int i = 0; i < 4; ++i) {
        #pragma unroll
        for (int rr = 0; rr < 4; ++rr) {
            float v = vmax[i][rr];
            v = fmaxf(v, __shfl_xor(v, 1));
            v = fmaxf(v, __shfl_xor(v, 2));
            v = fmaxf(v, __shfl_xor(v, 4));
            v = fmaxf(v, __shfl_xor(v, 8));
            if (l15 == 0) {
                int rloc = wwr * 64 + i * 16 + l4 * 4 + rr;
                red[rloc * 2 + wwc] = v;
            }
        }
    }
    __syncthreads();
    if (tid < 128) {
        float v = fmaxf(red[tid * 2 + 0], red[tid * 2 + 1]);
        atomicMax(&rowmax[n0 + tid], ordf(v));
    }
}

// ---------- kernel 3a: BCE + novelty weight, per-block partial sums ----------

__global__ __launch_bounds__(256) void finalize1_kernel(
    const float* __restrict__ pred, const float* __restrict__ targ,
    const u32* __restrict__ rowmax, float* __restrict__ partial, int N)
{
    __shared__ float ws4[4];
    const int tid = threadIdx.x;
    const int i = blockIdx.x * 256 + tid;

    float sv = 0.f;
    if (i < N) {
        float x = pred[i];
        float t = targ[i];
        float bl = fmaxf(x, 0.f) + log1pf(expf(-fabsf(x))) - x * t;
        float ms = unordf(rowmax[i]);
        sv = bl * (1.0f + 2.0f * (1.0f - ms));
    }
    #pragma unroll
    for (int m = 1; m <= 32; m <<= 1) sv += __shfl_xor(sv, m);
    if ((tid & 63) == 0) ws4[tid >> 6] = sv;
    __syncthreads();
    if (tid == 0) partial[blockIdx.x] = ws4[0] + ws4[1] + ws4[2] + ws4[3];
}

// ---------- kernel 3b: final reduce ----------

__global__ __launch_bounds__(64) void finalize2_kernel(
    const float* __restrict__ partial, float* __restrict__ out, int nb, int N)
{
    float sv = 0.f;
    for (int i = threadIdx.x; i < nb; i += 64) sv += partial[i];
    #pragma unroll
    for (int m = 1; m <= 32; m <<= 1) sv += __shfl_xor(sv, m);
    if (threadIdx.x == 0) out[0] = sv / (float)N;
}

// ---------- launch ----------

extern "C" void kernel_launch(void* const* d_in, const int* in_sizes, int n_in,
                              void* d_out, int out_size, void* d_ws, size_t ws_size,
                              hipStream_t stream) {
    const float* pred = (const float*)d_in[0];
    const float* targ = (const float*)d_in[1];
    const float* feat = (const float*)d_in[2];
    const float* memf = (const float*)d_in[3];
    const int N = in_sizes[0];
    const int D = in_sizes[2] / N;
    const int M = in_sizes[3] / D;
    float* out = (float*)d_out;

    u8* fb8 = (u8*)d_ws;                           // N*D fp8
    u8* mb8 = fb8 + (size_t)N * D;                 // M*D fp8
    u32* rowmax = (u32*)(mb8 + (size_t)M * D);     // N u32
    float* partial = (float*)(rowmax + N);         // nb floats

    const int rows = N + M;
    const int nb = (N + 255) / 256;
    norm_kernel<<<dim3((rows + 3) / 4), dim3(256), 0, stream>>>(
        feat, memf, fb8, mb8, rowmax, N, M, D);
    gemm_max_kernel<<<dim3(M / CPB, N / 128), dim3(256), 0, stream>>>(
        fb8, mb8, rowmax, N, M, D);
    finalize1_kernel<<<dim3(nb), dim3(256), 0, stream>>>(
        pred, targ, rowmax, partial, N);
    finalize2_kernel<<<dim3(1), dim3(64), 0, stream>>>(partial, out, nb, N);
}

// Round 15
// 50.234 us; speedup vs baseline: 2.1036x; 1.0517x over previous
//
#include <hip/hip_runtime.h>
#include <math.h>

typedef unsigned char u8;
typedef unsigned short u16;
typedef unsigned int u32;
typedef __attribute__((ext_vector_type(8))) int i32x8;
typedef __attribute__((ext_vector_type(4))) float f32x4;

#define SC1 0x7F7F7F7F   // e8m0 scale bytes = 127 -> 2^0 = 1.0
#define CPB 1024         // cols per block
#define NCT (CPB / 128)  // col-tiles per block = 8

// ---------- helpers ----------

__device__ __forceinline__ u32 ordf(float f) {
    u32 u = __float_as_uint(f);
    return (u & 0x80000000u) ? ~u : (u | 0x80000000u);
}
__device__ __forceinline__ float unordf(u32 u) {
    u = (u & 0x80000000u) ? (u & 0x7FFFFFFFu) : ~u;
    return __uint_as_float(u);
}

// f32 -> OCP e4m3fn with RNE. Assumes finite |x| <= 1.
__device__ __forceinline__ u32 f2e4m3(float x) {
    u32 u = __float_as_uint(x);
    u32 sgn = (u >> 24) & 0x80u;
    int ne = (int)((u >> 23) & 0xFF) - 120;   // e4m3 biased exponent
    if (ne >= 1) {
        u32 m = u & 0x7FFFFFu;
        u32 keep = m >> 20;
        u32 rest = m & 0xFFFFFu;
        keep += (rest > 0x80000u) || (rest == 0x80000u && (keep & 1u));
        if (keep == 8u) { keep = 0u; ne += 1; }
        return sgn | ((u32)ne << 3) | keep;
    }
    float ax = __uint_as_float(u & 0x7FFFFFFFu);
    u32 f = (u32)__builtin_rintf(ax * 512.0f);
    if (f >= 8u) return sgn | 0x08u;
    return sgn | f;
}

// async global->LDS, 16B per lane (dest = wave-uniform base + lane*16)
__device__ __forceinline__ void gload_lds16(const void* gsrc, void* ldst) {
    __builtin_amdgcn_global_load_lds(
        (const __attribute__((address_space(1))) void*)gsrc,
        (__attribute__((address_space(3))) void*)ldst,
        16, 0, 0);
}

__device__ __forceinline__ i32x8 ldfrag(const char* plo, const char* phi) {
    int4 lo = *(const int4*)plo;
    int4 hi = *(const int4*)phi;
    i32x8 r = {lo.x, lo.y, lo.z, lo.w, hi.x, hi.y, hi.z, hi.w};
    return r;
}

#define BARRIER do { __builtin_amdgcn_sched_barrier(0); \
                     __builtin_amdgcn_s_barrier(); \
                     __builtin_amdgcn_sched_barrier(0); } while (0)
#define VMCNT(n) do { asm volatile("s_waitcnt vmcnt(" #n ")" ::: "memory"); \
                      __builtin_amdgcn_sched_barrier(0); } while (0)

// ---------- kernel 1: normalize rows -> fp8 e4m3; init rowmax ----------

__global__ __launch_bounds__(256) void norm_kernel(
    const float* __restrict__ feat, const float* __restrict__ memf,
    u8* __restrict__ fb, u8* __restrict__ mb, u32* __restrict__ rowmax,
    int N, int M, int D)
{
    const int lane = threadIdx.x & 63;
    const int wid  = threadIdx.x >> 6;
    const int rid  = blockIdx.x * 4 + wid;
    if (rid >= N + M) return;

    const float* src;
    u8* dst;
    if (rid < N) { src = feat + (size_t)rid * D; dst = fb + (size_t)rid * D; }
    else         { src = memf + (size_t)(rid - N) * D; dst = mb + (size_t)(rid - N) * D; }

    float4 v0 = *(const float4*)(src + lane * 8);
    float4 v1 = *(const float4*)(src + lane * 8 + 4);
    float ss = v0.x*v0.x + v0.y*v0.y + v0.z*v0.z + v0.w*v0.w
             + v1.x*v1.x + v1.y*v1.y + v1.z*v1.z + v1.w*v1.w;
    #pragma unroll
    for (int m = 1; m <= 32; m <<= 1) ss += __shfl_xor(ss, m);

    float inv = 1.0f / fmaxf(sqrtf(ss), 1e-8f);

    u32 w0 =  f2e4m3(v0.x * inv)        | (f2e4m3(v0.y * inv) << 8)
           | (f2e4m3(v0.z * inv) << 16) | (f2e4m3(v0.w * inv) << 24);
    u32 w1 =  f2e4m3(v1.x * inv)        | (f2e4m3(v1.y * inv) << 8)
           | (f2e4m3(v1.z * inv) << 16) | (f2e4m3(v1.w * inv) << 24);
    *(uint2*)(dst + lane * 8) = make_uint2(w0, w1);

    if (rid < N && lane == 0) rowmax[rid] = 0u;   // below any real sim
}

// ---------- kernel 2: A-in-registers MX-fp8 GEMM + fused row-max ----------
// CHAMPION STRUCTURE (r9, 50.2us total). Block = 128-row stripe x 1024 cols
// (8 col-tiles of 128). Grid (8,64) = 512 = 2 blocks/CU -> 2 waves/SIMD;
// inter-block TLP hides the per-tile staging drain (r10-r14 ablations: every
// added barrier/buffer scheme regressed vs this).
// Per wave (2x2): A 64 rows x K=512 held ENTIRELY in regs: areg[4][4] i32x8
// (128 VGPR) -> zero LDS traffic for A. B: 64KB tile (4 kt x [128 rows][128B])
// staged per col-tile via gload_lds (single-buffered), frags read via XOR-
// swizzled b128 pairs (layout verified r7-r14). Per-ct epilogue folds acc into
// a running vmax and resets acc.
// MFMA: mfma_scale_f32_16x16x128_f8f6f4, fmt=0 (e4m3), scales = 1.0.

#define STAGE_B(gB) do { \
    _Pragma("unroll") \
    for (int kt_ = 0; kt_ < 4; ++kt_) \
      _Pragma("unroll") \
      for (int p_ = 0; p_ < 4; ++p_) \
        gload_lds16((gB) + (size_t)(p_ * 32) * D + kt_ * 128, \
                    &L[kt_ * 16384 + p_ * 4096 + tid * 16]); \
  } while (0)

__global__ __launch_bounds__(256, 2) void gemm_max_kernel(
    const u8* __restrict__ fb, const u8* __restrict__ mb,
    u32* __restrict__ rowmax, int N, int M, int D)
{
    __shared__ __align__(16) u8 L[65536];   // B tile only

    const int tid  = threadIdx.x;
    const int lane = tid & 63;
    const int wid  = tid >> 6;
    const int wwr  = wid >> 1;      // A row-half (0..1)
    const int wwc  = wid & 1;       // B col-half (0..1)
    const int l15  = lane & 15;
    const int l4   = lane >> 4;
    const int n0   = blockIdx.y * 128;
    const int m0   = blockIdx.x * CPB;

    // B staging: per-thread pre-swizzled global base (row = t8, chunk = tid&7)
    const int t8   = tid >> 3;
    const int swz  = ((tid & 7) ^ (t8 & 7)) * 16;

    // B ds_read: per-lane swizzled k-offsets (two b128 per frag)
    const int s    = (l15 & 7) << 4;
    const int oLo  = (l4 * 32) ^ s;
    const int oHi  = (l4 * 32 + 16) ^ s;
    const char* Lb = (const char*)L;
    const char* Bbase = Lb + (wwc * 64 + l15) * 128;   // + kt*16384 + j*2048

    // ---- prologue: issue B stage for ct=0, then load A stripe into regs ----
    const u8* gB0 = mb + (size_t)(m0 + t8) * D + swz;
    STAGE_B(gB0);

    const u8* gArow = fb + (size_t)(n0 + wwr * 64 + l15) * D + l4 * 32;
    i32x8 areg[4][4];   // [row-frag i][k-tile kt], 128 VGPR
    #pragma unroll
    for (int i = 0; i < 4; ++i)
        #pragma unroll
        for (int kt = 0; kt < 4; ++kt)
            areg[i][kt] = *(const i32x8*)(gArow + (size_t)(i * 16) * D + kt * 128);

    VMCNT(0);
    BARRIER;

    f32x4 acc[4][4] = {};
    float vmax[4][4];
    #pragma unroll
    for (int i = 0; i < 4; ++i)
        #pragma unroll
        for (int rr = 0; rr < 4; ++rr) vmax[i][rr] = -1e30f;

    for (int ct = 0; ct < NCT; ++ct) {
        if (ct > 0) {
            BARRIER;   // all waves done reading previous B tile (lgkm-certified)
            const u8* gB = mb + (size_t)(m0 + ct * 128 + t8) * D + swz;
            STAGE_B(gB);
            VMCNT(0);
            BARRIER;
        }

        // ---- compute: 4 k-tiles x (4 B-frag reads + 16 MFMA) ----
        #pragma unroll
        for (int kt = 0; kt < 4; ++kt) {
            #pragma unroll
            for (int j = 0; j < 4; ++j) {
                i32x8 bfj = ldfrag(Bbase + kt * 16384 + j * 2048 + oLo,
                                   Bbase + kt * 16384 + j * 2048 + oHi);
                #pragma unroll
                for (int i = 0; i < 4; ++i)
                    acc[i][j] = __builtin_amdgcn_mfma_scale_f32_16x16x128_f8f6f4(
                        areg[i][kt], bfj, acc[i][j], 0, 0, 0, SC1, 0, SC1);
            }
        }

        // ---- fold this col-tile's sims into running max; reset acc ----
        #pragma unroll
        for (int i = 0; i < 4; ++i)
            #pragma unroll
            for (int rr = 0; rr < 4; ++rr) {
                float v = fmaxf(fmaxf(acc[i][0][rr], acc[i][1][rr]),
                                fmaxf(acc[i][2][rr], acc[i][3][rr]));
                vmax[i][rr] = fmaxf(vmax[i][rr], v);
            }
        #pragma unroll
        for (int i = 0; i < 4; ++i)
            #pragma unroll
            for (int j = 0; j < 4; ++j) acc[i][j] = (f32x4)0.0f;
    }

    // ---- epilogue: cross-lane + cross-wave max reduce; one atomic/row ----
    BARRIER;                      // protect L reuse
    float* red = (float*)L;       // [128][2]
    #pragma unroll
    for (int i = 0; i < 4; ++i) {
        #pragma unroll
        for (int rr = 0; rr < 4; ++rr) {
            float v = vmax[i][rr];
            v = fmaxf(v, __shfl_xor(v, 1));
            v = fmaxf(v, __shfl_xor(v, 2));
            v = fmaxf(v, __shfl_xor(v, 4));
            v = fmaxf(v, __shfl_xor(v, 8));
            if (l15 == 0) {
                int rloc = wwr * 64 + i * 16 + l4 * 4 + rr;
                red[rloc * 2 + wwc] = v;
            }
        }
    }
    __syncthreads();
    if (tid < 128) {
        float v = fmaxf(red[tid * 2 + 0], red[tid * 2 + 1]);
        atomicMax(&rowmax[n0 + tid], ordf(v));
    }
}

// ---------- kernel 3a: BCE + novelty weight, per-block partial sums ----------

__global__ __launch_bounds__(256) void finalize1_kernel(
    const float* __restrict__ pred, const float* __restrict__ targ,
    const u32* __restrict__ rowmax, float* __restrict__ partial, int N)
{
    __shared__ float ws4[4];
    const int tid = threadIdx.x;
    const int i = blockIdx.x * 256 + tid;

    float sv = 0.f;
    if (i < N) {
        float x = pred[i];
        float t = targ[i];
        float bl = fmaxf(x, 0.f) + log1pf(expf(-fabsf(x))) - x * t;
        float ms = unordf(rowmax[i]);
        sv = bl * (1.0f + 2.0f * (1.0f - ms));
    }
    #pragma unroll
    for (int m = 1; m <= 32; m <<= 1) sv += __shfl_xor(sv, m);
    if ((tid & 63) == 0) ws4[tid >> 6] = sv;
    __syncthreads();
    if (tid == 0) partial[blockIdx.x] = ws4[0] + ws4[1] + ws4[2] + ws4[3];
}

// ---------- kernel 3b: final reduce ----------

__global__ __launch_bounds__(64) void finalize2_kernel(
    const float* __restrict__ partial, float* __restrict__ out, int nb, int N)
{
    float sv = 0.f;
    for (int i = threadIdx.x; i < nb; i += 64) sv += partial[i];
    #pragma unroll
    for (int m = 1; m <= 32; m <<= 1) sv += __shfl_xor(sv, m);
    if (threadIdx.x == 0) out[0] = sv / (float)N;
}

// ---------- launch ----------

extern "C" void kernel_launch(void* const* d_in, const int* in_sizes, int n_in,
                              void* d_out, int out_size, void* d_ws, size_t ws_size,
                              hipStream_t stream) {
    const float* pred = (const float*)d_in[0];
    const float* targ = (const float*)d_in[1];
    const float* feat = (const float*)d_in[2];
    const float* memf = (const float*)d_in[3];
    const int N = in_sizes[0];
    const int D = in_sizes[2] / N;
    const int M = in_sizes[3] / D;
    float* out = (float*)d_out;

    u8* fb8 = (u8*)d_ws;                           // N*D fp8
    u8* mb8 = fb8 + (size_t)N * D;                 // M*D fp8
    u32* rowmax = (u32*)(mb8 + (size_t)M * D);     // N u32
    float* partial = (float*)(rowmax + N);         // nb floats

    const int rows = N + M;
    const int nb = (N + 255) / 256;
    norm_kernel<<<dim3((rows + 3) / 4), dim3(256), 0, stream>>>(
        feat, memf, fb8, mb8, rowmax, N, M, D);
    gemm_max_kernel<<<dim3(M / CPB, N / 128), dim3(256), 0, stream>>>(
        fb8, mb8, rowmax, N, M, D);
    finalize1_kernel<<<dim3(nb), dim3(256), 0, stream>>>(
        pred, targ, rowmax, partial, N);
    finalize2_kernel<<<dim3(1), dim3(64), 0, stream>>>(partial, out, nb, N);
}